// Round 7
// baseline (344.523 us; speedup 1.0000x reference)
//
#include <hip/hip_runtime.h>
#include <hip/hip_bf16.h>

#define NIMG 8
#define HW 56
#define CDIM 256
#define TOK (NIMG*HW*HW)        // 25088
#define NWIN 49
#define NPW (NIMG*NWIN)         // 392
#define ATT_SCALE 0.0625f       // 256^-0.5

typedef __attribute__((ext_vector_type(8))) short short8;
typedef __attribute__((ext_vector_type(4))) short short4v;
typedef __attribute__((ext_vector_type(4))) float f32x4;

// ---- workspace layout (bytes, 16B aligned) ----
static const size_t OFF_WQKV  = 0;           // 768x256 bf16
static const size_t OFF_WWO   = 393216;      // 256x256 bf16
static const size_t OFF_W1    = 524288;      // 1024x256 bf16
static const size_t OFF_W2    = 1048576;     // 256x1024 bf16
static const size_t OFF_XLN   = 1572864;     // 25088x256 bf16 (reused: ywo)
static const size_t OFF_QKV   = 14417920;    // 25088x768 bf16
static const size_t OFF_QKWIN = 52953088;    // 392x512 f32
static const size_t OFF_RIDX  = 53755904;    // 392x4 int
static const size_t OFF_ATTN  = 53762176;    // 25088x256 bf16 (reused: h2)
static const size_t OFF_HMID  = OFF_XLN;     // 25088x1024 bf16 spans XLN+QKV regions

__device__ __forceinline__ float gelu_exact(float v) {
    return 0.5f * v * (1.f + erff(v * 0.70710678118654752f));
}
__device__ __forceinline__ short f2bs(float x) {
    __hip_bfloat16 h = __float2bfloat16(x);
    return *(short*)&h;
}
__device__ __forceinline__ float bs2f(short s) {
    return __uint_as_float(((unsigned)(unsigned short)s) << 16);
}
// async global->LDS, 16B per lane; LDS dest is wave-uniform base + lane*16
__device__ __forceinline__ void gld16(const short* g, short* l) {
    __builtin_amdgcn_global_load_lds(
        (const __attribute__((address_space(1))) void*)g,
        (__attribute__((address_space(3))) void*)l, 16, 0, 0);
}

// ---------------- batched weight transpose+cast: 4 weights in one launch ----------------
__global__ __launch_bounds__(256) void transpose_cast4_k(const float* __restrict__ s0,
                                                         const float* __restrict__ s1,
                                                         const float* __restrict__ s2,
                                                         const float* __restrict__ s3,
                                                         __hip_bfloat16* __restrict__ d0,
                                                         __hip_bfloat16* __restrict__ d1,
                                                         __hip_bfloat16* __restrict__ d2,
                                                         __hip_bfloat16* __restrict__ d3) {
    int b = blockIdx.x;
    const float* src; __hip_bfloat16* dst; int K, N, l;
    if (b < 192)      { src = s0; dst = d0; K = 256;  N = 768;  l = b; }
    else if (b < 256) { src = s1; dst = d1; K = 256;  N = 256;  l = b - 192; }
    else if (b < 512) { src = s2; dst = d2; K = 256;  N = 1024; l = b - 256; }
    else              { src = s3; dst = d3; K = 1024; N = 256;  l = b - 512; }
    int nx = N / 32;
    int n0 = (l % nx) * 32, k0 = (l / nx) * 32;
    __shared__ float t[32][33];
    int tx = threadIdx.x & 31, ty = threadIdx.x >> 5;   // 32 x 8
    #pragma unroll
    for (int i = 0; i < 32; i += 8)
        t[ty + i][tx] = src[(size_t)(k0 + ty + i) * N + n0 + tx];
    __syncthreads();
    #pragma unroll
    for (int i = 0; i < 32; i += 8)
        dst[(size_t)(n0 + ty + i) * K + k0 + tx] = __float2bfloat16(t[tx][ty + i]);
}

// ---------------- LayerNorm: wave per token, lane = 4 channels ----------------
__global__ __launch_bounds__(256) void ln_bf_k(const float* __restrict__ in,
                                               const float* __restrict__ g,
                                               const float* __restrict__ b,
                                               short* __restrict__ out, int remap) {
    int t = blockIdx.x * 4 + (threadIdx.x >> 6);
    int lane = threadIdx.x & 63;
    float4 v = *(const float4*)(in + (size_t)t * 256 + lane * 4);
    float s = v.x + v.y + v.z + v.w;
    float s2 = v.x * v.x + v.y * v.y + v.z * v.z + v.w * v.w;
    #pragma unroll
    for (int o = 32; o > 0; o >>= 1) {
        s  += __shfl_xor(s, o);
        s2 += __shfl_xor(s2, o);
    }
    float mu = s * (1.f / 256.f);
    float rstd = rsqrtf(s2 * (1.f / 256.f) - mu * mu + 1e-6f);
    float4 gv = *(const float4*)(g + lane * 4);
    float4 bv = *(const float4*)(b + lane * 4);
    short4v o;
    o[0] = f2bs((v.x - mu) * rstd * gv.x + bv.x);
    o[1] = f2bs((v.y - mu) * rstd * gv.y + bv.y);
    o[2] = f2bs((v.z - mu) * rstd * gv.z + bv.z);
    o[3] = f2bs((v.w - mu) * rstd * gv.w + bv.w);
    size_t tb;
    if (remap) {
        int n = t / 3136, rem = t % 3136, y = rem / 56, x = rem % 56;
        int p = (y >> 3) * 7 + (x >> 3);
        int si = (y & 7) * 8 + (x & 7);
        tb = (size_t)(n * 49 + p) * 64 + si;
    } else {
        tb = (size_t)t;
    }
    *(short4v*)(out + tb * 256 + lane * 4) = o;
}

// ---------------- m97-style bf16 MFMA GEMM: 128x128 tile, BK=32, global_load_lds ----------------
// MODE 0: bf16 out +bias. MODE 1: f32 out +bias+res. MODE 2: bf16 out gelu(+bias).
// LDS: unpadded As/Bs[128][32] shorts (8KB each); epilogue reuses 20KB for transpose.
template<int MODE>
__global__ __launch_bounds__(256) void gemm97(const short* __restrict__ A,
                                              const short* __restrict__ Bt,
                                              const float* __restrict__ bias,
                                              const float* __restrict__ res, void* Cv,
                                              int M, int N, int K) {
    const int bn = blockIdx.x * 128;
    const int bm = blockIdx.y * 128;
    const int tid = threadIdx.x;
    const int wave = tid >> 6, lane = tid & 63;
    const int l15 = lane & 15, quad = lane >> 4;
    const int wm = (wave & 1) * 64, wn = (wave >> 1) * 64;

    __shared__ __align__(16) short smem[10240];   // 20.5KB: staging 16KB | epilogue 20KB
    short* As = smem;            // [128][32] unpadded
    short* Bs = smem + 4096;     // [128][32] unpadded

    f32x4 acc[4][4];
    #pragma unroll
    for (int i = 0; i < 4; ++i)
        #pragma unroll
        for (int j = 0; j < 4; ++j) acc[i][j] = (f32x4){0.f, 0.f, 0.f, 0.f};

    // staging: wave handles chunks 2*wave, 2*wave+1 (16 rows x 32k = 1KB each) for A and B
    const int ca = wave * 2;
    const int crow = lane >> 2;           // 0..15 row within chunk
    const int ckq = (lane & 3) * 8;       // 0,8,16,24
    const short* ga0 = A  + (size_t)(bm + ca * 16 + crow) * K + ckq;
    const short* ga1 = ga0 + (size_t)16 * K;
    const short* gb0 = Bt + (size_t)(bn + ca * 16 + crow) * K + ckq;
    const short* gb1 = gb0 + (size_t)16 * K;
    short* la0 = As + ca * 512;
    short* lb0 = Bs + ca * 512;

    for (int k0 = 0; k0 < K; k0 += 32) {
        gld16(ga0 + k0, la0);
        gld16(ga1 + k0, la0 + 512);
        gld16(gb0 + k0, lb0);
        gld16(gb1 + k0, lb0 + 512);
        __syncthreads();   // drains vmcnt (DMA) before reads
        short8 af[4], bfr[4];
        #pragma unroll
        for (int i = 0; i < 4; ++i)
            af[i] = *(const short8*)&As[(wm + i * 16 + l15) * 32 + quad * 8];
        #pragma unroll
        for (int j = 0; j < 4; ++j)
            bfr[j] = *(const short8*)&Bs[(wn + j * 16 + l15) * 32 + quad * 8];
        #pragma unroll
        for (int i = 0; i < 4; ++i)
            #pragma unroll
            for (int j = 0; j < 4; ++j)
                acc[i][j] = __builtin_amdgcn_mfma_f32_16x16x32_bf16(af[i], bfr[j], acc[i][j], 0, 0, 0);
        __syncthreads();   // all reads done before next iter's DMA overwrites
    }

    if (MODE == 1) {
        #pragma unroll
        for (int i = 0; i < 4; ++i) {
            int row = bm + wm + i * 16 + quad * 4;
            #pragma unroll
            for (int j = 0; j < 4; ++j) {
                int col = bn + wn + j * 16 + l15;
                float bia = bias[col];
                #pragma unroll
                for (int r = 0; r < 4; ++r) {
                    size_t idx = (size_t)(row + r) * N + col;
                    ((float*)Cv)[idx] = acc[i][j][r] + bia + res[idx];
                }
            }
        }
    } else {
        // bf16 out via per-wave LDS transpose (4 regions of 2560 shorts, stride 40)
        float biasv[4];
        #pragma unroll
        for (int j = 0; j < 4; ++j) biasv[j] = bias[bn + wn + j * 16 + l15];
        short* ep = &smem[wave * 2560];
        short* outp = (short*)Cv;
        #pragma unroll
        for (int p = 0; p < 2; ++p) {
            #pragma unroll
            for (int i = 0; i < 4; ++i)
                #pragma unroll
                for (int jj = 0; jj < 2; ++jj) {
                    int j = p * 2 + jj;
                    #pragma unroll
                    for (int r = 0; r < 4; ++r) {
                        float v = acc[i][j][r] + biasv[j];
                        if (MODE == 2) v = gelu_exact(v);
                        ep[(i * 16 + quad * 4 + r) * 40 + jj * 16 + l15] = f2bs(v);
                    }
                }
            __builtin_amdgcn_s_waitcnt(0);   // wave-local drain of LDS writes
            int c = lane & 3;
            #pragma unroll
            for (int rr = 0; rr < 4; ++rr) {
                int row = rr * 16 + (lane >> 2);
                short8 v = *(const short8*)&ep[row * 40 + c * 8];
                *(short8*)&outp[(size_t)(bm + wm + row) * N + bn + wn + p * 32 + c * 8] = v;
            }
            __builtin_amdgcn_s_waitcnt(0);
        }
    }
}

// ---------------- window means of q,k: block per window, short8 loads ----------------
__global__ __launch_bounds__(256) void win_means_k(const short* __restrict__ qkv,
                                                   float* __restrict__ qkwin) {
    int w = blockIdx.x;
    int cg = (threadIdx.x & 63) * 8;
    int sp = threadIdx.x >> 6;
    float s[8] = {0.f, 0.f, 0.f, 0.f, 0.f, 0.f, 0.f, 0.f};
    const short* base = qkv + (size_t)w * 64 * 768 + cg;
    for (int si = sp; si < 64; si += 4) {
        short8 v = *(const short8*)(base + (size_t)si * 768);
        #pragma unroll
        for (int i = 0; i < 8; ++i) s[i] += bs2f(v[i]);
    }
    __shared__ float red[4][512];
    #pragma unroll
    for (int i = 0; i < 8; ++i) red[sp][cg + i] = s[i];
    __syncthreads();
    for (int c = threadIdx.x; c < 512; c += 256) {
        float t = red[0][c] + red[1][c] + red[2][c] + red[3][c];
        qkwin[(size_t)w * 512 + c] = t * (1.f / 64.f);
    }
}

// ---------------- routing top-k ----------------
__global__ __launch_bounds__(64) void route_k(const float* __restrict__ qkwin,
                                              int* __restrict__ ridx) {
    int w = blockIdx.x;
    int n = w / 49;
    int tid = threadIdx.x;
    __shared__ float qv[256];
    __shared__ float lg[49];
    for (int i = tid; i < 256; i += 64) qv[i] = qkwin[(size_t)w * 512 + i] * ATT_SCALE;
    __syncthreads();
    if (tid < 49) {
        const float* kp = qkwin + (size_t)(n * 49 + tid) * 512 + 256;
        float d = 0.f;
        for (int cc = 0; cc < 256; ++cc) d += qv[cc] * kp[cc];
        lg[tid] = d;
    }
    __syncthreads();
    if (tid == 0) {
        #pragma unroll
        for (int t = 0; t < 4; ++t) {
            float best = -1e30f; int bi = 0;
            for (int j = 0; j < 49; ++j)
                if (lg[j] > best) { best = lg[j]; bi = j; }
            lg[bi] = -1e30f;
            ridx[w * 4 + t] = bi;
        }
    }
}

// ---------------- MFMA attention: block = (window, head), 4 waves x 16 queries ----------------
__global__ __launch_bounds__(256) void attn_mfma_k(const short* __restrict__ qkv,
                                                   const int* __restrict__ ridx,
                                                   short* __restrict__ attn) {
    const int blk = blockIdx.x;
    const int w = blk >> 3, h = blk & 7;
    const int n = w / 49;
    const int tid = threadIdx.x;
    const int wave = tid >> 6, lane = tid & 63;
    const int l15 = lane & 15, quad = lane >> 4;

    __shared__ __align__(16) short Ks[256 * 40];
    __shared__ __align__(16) short Vt[32 * 264];
    __shared__ __align__(16) short Ps[4 * 16 * 264];
    __shared__ int rs4[4];
    if (tid < 4) rs4[tid] = ridx[w * 4 + tid];
    __syncthreads();

    {
        int s = tid >> 2, kq = (tid & 3) * 8;
        #pragma unroll
        for (int u = 0; u < 4; ++u) {
            int key = u * 64 + s;
            const short* src = qkv + ((size_t)(n * 49 + rs4[u]) * 64 + s) * 768 + 256 + h * 32 + kq;
            *(short8*)&Ks[key * 40 + kq] = *(const short8*)src;
        }
    }
    {
        int key = tid;
        int t = key >> 6, s = key & 63;
        const short* src = qkv + ((size_t)(n * 49 + rs4[t]) * 64 + s) * 768 + 512 + h * 32;
        #pragma unroll
        for (int u = 0; u < 4; ++u) {
            short8 v = *(const short8*)(src + u * 8);
            #pragma unroll
            for (int i = 0; i < 8; ++i)
                Vt[(u * 8 + i) * 264 + key] = v[i];
        }
    }
    __syncthreads();

    const short* qp = qkv + ((size_t)w * 64 + wave * 16 + l15) * 768 + h * 32 + quad * 8;
    short8 qf = *(const short8*)qp;

    f32x4 st[16];
    #pragma unroll
    for (int j = 0; j < 16; ++j) {
        short8 kf = *(const short8*)&Ks[(j * 16 + l15) * 40 + quad * 8];
        st[j] = __builtin_amdgcn_mfma_f32_16x16x32_bf16(qf, kf, (f32x4){0.f, 0.f, 0.f, 0.f}, 0, 0, 0);
    }

    float lr[4];
    short* pw = &Ps[wave * 16 * 264];
    #pragma unroll
    for (int r = 0; r < 4; ++r) {
        float mx = -1e30f;
        #pragma unroll
        for (int j = 0; j < 16; ++j) mx = fmaxf(mx, st[j][r]);
        #pragma unroll
        for (int off = 1; off < 16; off <<= 1) mx = fmaxf(mx, __shfl_xor(mx, off));
        float sum = 0.f;
        #pragma unroll
        for (int j = 0; j < 16; ++j) {
            float p = __expf((st[j][r] - mx) * ATT_SCALE);
            sum += p;
            pw[(quad * 4 + r) * 264 + j * 16 + l15] = f2bs(p);
        }
        #pragma unroll
        for (int off = 1; off < 16; off <<= 1) sum += __shfl_xor(sum, off);
        lr[r] = sum;
    }
    __syncthreads();

    f32x4 oc[2] = {(f32x4){0.f,0.f,0.f,0.f}, (f32x4){0.f,0.f,0.f,0.f}};
    #pragma unroll
    for (int kk = 0; kk < 8; ++kk) {
        short8 pf = *(const short8*)&pw[l15 * 264 + kk * 32 + quad * 8];
        #pragma unroll
        for (int jj = 0; jj < 2; ++jj) {
            short8 vf = *(const short8*)&Vt[(jj * 16 + l15) * 264 + kk * 32 + quad * 8];
            oc[jj] = __builtin_amdgcn_mfma_f32_16x16x32_bf16(pf, vf, oc[jj], 0, 0, 0);
        }
    }

    short* op = attn + ((size_t)w * 64 + wave * 16) * 256 + h * 32;
    #pragma unroll
    for (int jj = 0; jj < 2; ++jj)
        #pragma unroll
        for (int r = 0; r < 4; ++r)
            op[(size_t)(quad * 4 + r) * 256 + jj * 16 + l15] = f2bs(oc[jj][r] / lr[r]);
}

// ---------------- LePE 5x5 dwconv + combine (vectorized 8-ch per thread) ----------------
__global__ __launch_bounds__(256) void lepe_k(const short* __restrict__ qkv,
                                              const short* __restrict__ attn,
                                              const float* __restrict__ lw,
                                              const float* __restrict__ lb,
                                              short* __restrict__ ywo) {
    int t = blockIdx.x * 8 + (threadIdx.x >> 5);
    int c0 = (threadIdx.x & 31) * 8;
    int n = t / 3136, rem = t % 3136, y = rem / 56, x = rem % 56;
    float sum[8];
    {
        float4 b0 = *(const float4*)(lb + c0), b1 = *(const float4*)(lb + c0 + 4);
        sum[0] = b0.x; sum[1] = b0.y; sum[2] = b0.z; sum[3] = b0.w;
        sum[4] = b1.x; sum[5] = b1.y; sum[6] = b1.z; sum[7] = b1.w;
    }
    #pragma unroll
    for (int ky = 0; ky < 5; ++ky) {
        int yy = y + ky - 2;
        if ((unsigned)yy >= 56u) continue;
        #pragma unroll
        for (int kx = 0; kx < 5; ++kx) {
            int xx = x + kx - 2;
            if ((unsigned)xx >= 56u) continue;
            int p = (yy >> 3) * 7 + (xx >> 3);
            int si = (yy & 7) * 8 + (xx & 7);
            short8 v = *(const short8*)(qkv + ((size_t)(n * 49 + p) * 64 + si) * 768 + 512 + c0);
            const float* wp = lw + (ky * 5 + kx) * 256 + c0;
            float4 w0 = *(const float4*)wp, w1 = *(const float4*)(wp + 4);
            sum[0] += bs2f(v[0]) * w0.x; sum[1] += bs2f(v[1]) * w0.y;
            sum[2] += bs2f(v[2]) * w0.z; sum[3] += bs2f(v[3]) * w0.w;
            sum[4] += bs2f(v[4]) * w1.x; sum[5] += bs2f(v[5]) * w1.y;
            sum[6] += bs2f(v[6]) * w1.z; sum[7] += bs2f(v[7]) * w1.w;
        }
    }
    int p0 = (y >> 3) * 7 + (x >> 3);
    int s0 = (y & 7) * 8 + (x & 7);
    short8 a = *(const short8*)(attn + ((size_t)(n * 49 + p0) * 64 + s0) * 256 + c0);
    short8 o;
    #pragma unroll
    for (int i = 0; i < 8; ++i) o[i] = f2bs(sum[i] + bs2f(a[i]));
    *(short8*)(ywo + (size_t)t * 256 + c0) = o;
}

extern "C" void kernel_launch(void* const* d_in, const int* in_sizes, int n_in,
                              void* d_out, int out_size, void* d_ws, size_t ws_size,
                              hipStream_t stream) {
    const float* x      = (const float*)d_in[0];
    const float* ln1_g  = (const float*)d_in[1];
    const float* ln1_b  = (const float*)d_in[2];
    const float* qkv_w  = (const float*)d_in[3];
    const float* qkv_b  = (const float*)d_in[4];
    const float* lepe_w = (const float*)d_in[5];
    const float* lepe_b = (const float*)d_in[6];
    const float* wo_w   = (const float*)d_in[7];
    const float* wo_b   = (const float*)d_in[8];
    const float* ln2_g  = (const float*)d_in[9];
    const float* ln2_b  = (const float*)d_in[10];
    const float* mlp_w1 = (const float*)d_in[11];
    const float* mlp_b1 = (const float*)d_in[12];
    const float* mlp_w2 = (const float*)d_in[13];
    const float* mlp_b2 = (const float*)d_in[14];
    float* out = (float*)d_out;

    char* ws = (char*)d_ws;
    __hip_bfloat16* wqkvT = (__hip_bfloat16*)(ws + OFF_WQKV);
    __hip_bfloat16* wwoT  = (__hip_bfloat16*)(ws + OFF_WWO);
    __hip_bfloat16* w1T   = (__hip_bfloat16*)(ws + OFF_W1);
    __hip_bfloat16* w2T   = (__hip_bfloat16*)(ws + OFF_W2);
    short* xln   = (short*)(ws + OFF_XLN);
    short* qkvb  = (short*)(ws + OFF_QKV);
    float* qkwin = (float*)(ws + OFF_QKWIN);
    int*   ridx  = (int*)(ws + OFF_RIDX);
    short* attnb = (short*)(ws + OFF_ATTN);
    short* ywo   = (short*)(ws + OFF_XLN);    // reuse
    short* h2    = (short*)(ws + OFF_ATTN);   // reuse
    short* hmid  = (short*)(ws + OFF_HMID);   // reuse XLN+QKV span

    // 0. all weights -> bf16 transposed (N x K), one launch
    transpose_cast4_k<<<768, 256, 0, stream>>>(qkv_w, wo_w, mlp_w1, mlp_w2,
                                               wqkvT, wwoT, w1T, w2T);
    // 1. LN1 -> xln bf16 (window order)
    ln_bf_k<<<TOK/4, 256, 0, stream>>>(x, ln1_g, ln1_b, xln, 1);
    // 2. qkv GEMM -> bf16
    gemm97<0><<<dim3(6, 196), 256, 0, stream>>>(xln, (const short*)wqkvT,
                                                qkv_b, nullptr, qkvb, TOK, 768, 256);
    // 3. window means
    win_means_k<<<NPW, 256, 0, stream>>>(qkvb, qkwin);
    // 4. routing
    route_k<<<NPW, 64, 0, stream>>>(qkwin, ridx);
    // 5. attention (MFMA) -> bf16
    attn_mfma_k<<<NPW * 8, 256, 0, stream>>>(qkvb, ridx, attnb);
    // 6. lepe + combine -> ywo bf16 (image order)
    lepe_k<<<TOK/8, 256, 0, stream>>>(qkvb, attnb, lepe_w, lepe_b, ywo);
    // 7. wo GEMM + x residual -> d_out f32
    gemm97<1><<<dim3(2, 196), 256, 0, stream>>>(ywo, (const short*)wwoT,
                                                wo_b, x, out, TOK, 256, 256);
    // 8. LN2 -> h2 bf16
    ln_bf_k<<<TOK/4, 256, 0, stream>>>(out, ln2_g, ln2_b, h2, 0);
    // 9. MLP1 GEMM + gelu -> hmid bf16
    gemm97<2><<<dim3(8, 196), 256, 0, stream>>>(h2, (const short*)w1T,
                                                mlp_b1, nullptr, hmid, TOK, 1024, 256);
    // 10. MLP2 GEMM + bias + residual -> d_out f32
    gemm97<1><<<dim3(2, 196), 256, 0, stream>>>(hmid, (const short*)w2T,
                                                mlp_b2, out, out, TOK, 256, 1024);
}

// Round 9
// 318.752 us; speedup vs baseline: 1.0809x; 1.0809x over previous
//
#include <hip/hip_runtime.h>
#include <hip/hip_bf16.h>

#define NIMG 8
#define HW 56
#define CDIM 256
#define TOK (NIMG*HW*HW)        // 25088
#define NWIN 49
#define NPW (NIMG*NWIN)         // 392
#define ATT_SCALE 0.0625f       // 256^-0.5

typedef __attribute__((ext_vector_type(8))) short short8;
typedef __attribute__((ext_vector_type(4))) short short4v;
typedef __attribute__((ext_vector_type(4))) float f32x4;

// ---- workspace layout (bytes, 16B aligned) ----
static const size_t OFF_WQKV  = 0;           // 768x256 bf16
static const size_t OFF_WWO   = 393216;      // 256x256 bf16
static const size_t OFF_W1    = 524288;      // 1024x256 bf16
static const size_t OFF_W2    = 1048576;     // 256x1024 bf16
static const size_t OFF_XLN   = 1572864;     // 25088x256 bf16 (reused: ywo)
static const size_t OFF_QKV   = 14417920;    // 25088x768 bf16
static const size_t OFF_QKWIN = 52953088;    // 392x512 f32
static const size_t OFF_RIDX  = 53755904;    // 392x4 int
static const size_t OFF_ATTN  = 53762176;    // 25088x256 bf16 (reused: h2)
static const size_t OFF_HMID  = OFF_XLN;     // 25088x1024 bf16 spans XLN+QKV regions

__device__ __forceinline__ float gelu_exact(float v) {
    return 0.5f * v * (1.f + erff(v * 0.70710678118654752f));
}
__device__ __forceinline__ short f2bs(float x) {
    __hip_bfloat16 h = __float2bfloat16(x);
    return *(short*)&h;
}
__device__ __forceinline__ float bs2f(short s) {
    return __uint_as_float(((unsigned)(unsigned short)s) << 16);
}
// async global->LDS, 16B per lane; LDS dest is wave-uniform base + lane*16
__device__ __forceinline__ void gld16(const short* g, short* l) {
    __builtin_amdgcn_global_load_lds(
        (const __attribute__((address_space(1))) void*)g,
        (__attribute__((address_space(3))) void*)l, 16, 0, 0);
}

// ---------------- batched weight transpose+cast: 4 weights in one launch ----------------
__global__ __launch_bounds__(256) void transpose_cast4_k(const float* __restrict__ s0,
                                                         const float* __restrict__ s1,
                                                         const float* __restrict__ s2,
                                                         const float* __restrict__ s3,
                                                         __hip_bfloat16* __restrict__ d0,
                                                         __hip_bfloat16* __restrict__ d1,
                                                         __hip_bfloat16* __restrict__ d2,
                                                         __hip_bfloat16* __restrict__ d3) {
    int b = blockIdx.x;
    const float* src; __hip_bfloat16* dst; int K, N, l;
    if (b < 192)      { src = s0; dst = d0; K = 256;  N = 768;  l = b; }
    else if (b < 256) { src = s1; dst = d1; K = 256;  N = 256;  l = b - 192; }
    else if (b < 512) { src = s2; dst = d2; K = 256;  N = 1024; l = b - 256; }
    else              { src = s3; dst = d3; K = 1024; N = 256;  l = b - 512; }
    int nx = N / 32;
    int n0 = (l % nx) * 32, k0 = (l / nx) * 32;
    __shared__ float t[32][33];
    int tx = threadIdx.x & 31, ty = threadIdx.x >> 5;   // 32 x 8
    #pragma unroll
    for (int i = 0; i < 32; i += 8)
        t[ty + i][tx] = src[(size_t)(k0 + ty + i) * N + n0 + tx];
    __syncthreads();
    #pragma unroll
    for (int i = 0; i < 32; i += 8)
        dst[(size_t)(n0 + ty + i) * K + k0 + tx] = __float2bfloat16(t[tx][ty + i]);
}

// ---------------- LayerNorm: wave per token, lane = 4 channels ----------------
__global__ __launch_bounds__(256) void ln_bf_k(const float* __restrict__ in,
                                               const float* __restrict__ g,
                                               const float* __restrict__ b,
                                               short* __restrict__ out, int remap) {
    int t = blockIdx.x * 4 + (threadIdx.x >> 6);
    int lane = threadIdx.x & 63;
    float4 v = *(const float4*)(in + (size_t)t * 256 + lane * 4);
    float s = v.x + v.y + v.z + v.w;
    float s2 = v.x * v.x + v.y * v.y + v.z * v.z + v.w * v.w;
    #pragma unroll
    for (int o = 32; o > 0; o >>= 1) {
        s  += __shfl_xor(s, o);
        s2 += __shfl_xor(s2, o);
    }
    float mu = s * (1.f / 256.f);
    float rstd = rsqrtf(s2 * (1.f / 256.f) - mu * mu + 1e-6f);
    float4 gv = *(const float4*)(g + lane * 4);
    float4 bv = *(const float4*)(b + lane * 4);
    short4v o;
    o[0] = f2bs((v.x - mu) * rstd * gv.x + bv.x);
    o[1] = f2bs((v.y - mu) * rstd * gv.y + bv.y);
    o[2] = f2bs((v.z - mu) * rstd * gv.z + bv.z);
    o[3] = f2bs((v.w - mu) * rstd * gv.w + bv.w);
    size_t tb;
    if (remap) {
        int n = t / 3136, rem = t % 3136, y = rem / 56, x = rem % 56;
        int p = (y >> 3) * 7 + (x >> 3);
        int si = (y & 7) * 8 + (x & 7);
        tb = (size_t)(n * 49 + p) * 64 + si;
    } else {
        tb = (size_t)t;
    }
    *(short4v*)(out + tb * 256 + lane * 4) = o;
}

// ---------------- m97-style bf16 MFMA GEMM: 128x128 tile, BK=32, global_load_lds ----------------
// MODE 0: bf16 out +bias. MODE 2: bf16 out gelu(+bias).
// QMEANS: rows are window-ordered (64/window); blocks with bn<512 also emit
//         per-window column means (+bias) into qkwin — fuses win_means_k.
template<int MODE, bool QMEANS>
__global__ __launch_bounds__(256) void gemm97(const short* __restrict__ A,
                                              const short* __restrict__ Bt,
                                              const float* __restrict__ bias,
                                              void* Cv, float* __restrict__ qkwin,
                                              int M, int N, int K) {
    const int bn = blockIdx.x * 128;
    const int bm = blockIdx.y * 128;
    const int tid = threadIdx.x;
    const int wave = tid >> 6, lane = tid & 63;
    const int l15 = lane & 15, quad = lane >> 4;
    const int wm = (wave & 1) * 64, wn = (wave >> 1) * 64;

    __shared__ __align__(16) short smem[10240];   // staging 16KB | epilogue 20KB
    short* As = smem;            // [128][32] unpadded
    short* Bs = smem + 4096;     // [128][32] unpadded

    f32x4 acc[4][4];
    #pragma unroll
    for (int i = 0; i < 4; ++i)
        #pragma unroll
        for (int j = 0; j < 4; ++j) acc[i][j] = (f32x4){0.f, 0.f, 0.f, 0.f};

    const int ca = wave * 2;
    const int crow = lane >> 2;
    const int ckq = (lane & 3) * 8;
    const short* ga0 = A  + (size_t)(bm + ca * 16 + crow) * K + ckq;
    const short* ga1 = ga0 + (size_t)16 * K;
    const short* gb0 = Bt + (size_t)(bn + ca * 16 + crow) * K + ckq;
    const short* gb1 = gb0 + (size_t)16 * K;
    short* la0 = As + ca * 512;
    short* lb0 = Bs + ca * 512;

    for (int k0 = 0; k0 < K; k0 += 32) {
        gld16(ga0 + k0, la0);
        gld16(ga1 + k0, la0 + 512);
        gld16(gb0 + k0, lb0);
        gld16(gb1 + k0, lb0 + 512);
        __syncthreads();
        short8 af[4], bfr[4];
        #pragma unroll
        for (int i = 0; i < 4; ++i)
            af[i] = *(const short8*)&As[(wm + i * 16 + l15) * 32 + quad * 8];
        #pragma unroll
        for (int j = 0; j < 4; ++j)
            bfr[j] = *(const short8*)&Bs[(wn + j * 16 + l15) * 32 + quad * 8];
        #pragma unroll
        for (int i = 0; i < 4; ++i)
            #pragma unroll
            for (int j = 0; j < 4; ++j)
                acc[i][j] = __builtin_amdgcn_mfma_f32_16x16x32_bf16(af[i], bfr[j], acc[i][j], 0, 0, 0);
        __syncthreads();
    }

    // fused window means of q,k (pre-bias acc sums + bias)
    if (QMEANS && bn < 512) {
        float s[4];
        #pragma unroll
        for (int j = 0; j < 4; ++j) {
            float t = 0.f;
            #pragma unroll
            for (int i = 0; i < 4; ++i)
                #pragma unroll
                for (int r = 0; r < 4; ++r) t += acc[i][j][r];
            t += __shfl_xor(t, 16);
            t += __shfl_xor(t, 32);
            s[j] = t;
        }
        float v = (quad == 0) ? s[0] : (quad == 1) ? s[1] : (quad == 2) ? s[2] : s[3];
        int col = bn + wn + quad * 16 + l15;
        int win = (bm + wm) >> 6;
        qkwin[(size_t)win * 512 + col] = v * (1.f / 64.f) + bias[col];
    }

    // bf16 out via per-wave LDS transpose (4 regions of 2560 shorts, stride 40)
    float biasv[4];
    #pragma unroll
    for (int j = 0; j < 4; ++j) biasv[j] = bias[bn + wn + j * 16 + l15];
    short* ep = &smem[wave * 2560];
    short* outp = (short*)Cv;
    #pragma unroll
    for (int p = 0; p < 2; ++p) {
        #pragma unroll
        for (int i = 0; i < 4; ++i)
            #pragma unroll
            for (int jj = 0; jj < 2; ++jj) {
                int j = p * 2 + jj;
                #pragma unroll
                for (int r = 0; r < 4; ++r) {
                    float v = acc[i][j][r] + biasv[j];
                    if (MODE == 2) v = gelu_exact(v);
                    ep[(i * 16 + quad * 4 + r) * 40 + jj * 16 + l15] = f2bs(v);
                }
            }
        __builtin_amdgcn_s_waitcnt(0);
        int c = lane & 3;
        #pragma unroll
        for (int rr = 0; rr < 4; ++rr) {
            int row = rr * 16 + (lane >> 2);
            short8 v = *(const short8*)&ep[row * 40 + c * 8];
            *(short8*)&outp[(size_t)(bm + wm + row) * N + bn + wn + p * 32 + c * 8] = v;
        }
        __builtin_amdgcn_s_waitcnt(0);
    }
}

// ---------------- small-N GEMM: 64Mx128N tile, f32 out +bias+res ----------------
__global__ __launch_bounds__(256) void gemm_s(const short* __restrict__ A,
                                              const short* __restrict__ Bt,
                                              const float* __restrict__ bias,
                                              const float* __restrict__ res,
                                              float* __restrict__ C,
                                              int M, int N, int K) {
    const int bn = blockIdx.x * 128;
    const int bm = blockIdx.y * 64;
    const int tid = threadIdx.x;
    const int wave = tid >> 6, lane = tid & 63;
    const int l15 = lane & 15, quad = lane >> 4;
    const int wm = (wave & 1) * 32, wn = (wave >> 1) * 64;

    __shared__ __align__(16) short As[64 * 32];   // 4KB = 2048 shorts
    __shared__ __align__(16) short Bs[128 * 32];  // 8KB = 4096 shorts

    f32x4 acc[2][4];
    #pragma unroll
    for (int i = 0; i < 2; ++i)
        #pragma unroll
        for (int j = 0; j < 4; ++j) acc[i][j] = (f32x4){0.f, 0.f, 0.f, 0.f};

    const int crow = lane >> 2;          // 0..15
    const int ckq = (lane & 3) * 8;
    const short* ga  = A  + (size_t)(bm + wave * 16 + crow) * K + ckq;
    const short* gb0 = Bt + (size_t)(bn + wave * 16 + crow) * K + ckq;
    const short* gb1 = gb0 + (size_t)64 * K;
    // each wave's gld16 covers 64 lanes x 16B = 512 shorts = 16 rows
    short* la  = As + wave * 512;
    short* lb0 = Bs + wave * 512;
    short* lb1 = Bs + 2048 + wave * 512;

    for (int k0 = 0; k0 < K; k0 += 32) {
        gld16(ga + k0, la);
        gld16(gb0 + k0, lb0);
        gld16(gb1 + k0, lb1);
        __syncthreads();
        short8 af[2], bfr[4];
        #pragma unroll
        for (int i = 0; i < 2; ++i)
            af[i] = *(const short8*)&As[(wm + i * 16 + l15) * 32 + quad * 8];
        #pragma unroll
        for (int j = 0; j < 4; ++j)
            bfr[j] = *(const short8*)&Bs[(wn + j * 16 + l15) * 32 + quad * 8];
        #pragma unroll
        for (int i = 0; i < 2; ++i)
            #pragma unroll
            for (int j = 0; j < 4; ++j)
                acc[i][j] = __builtin_amdgcn_mfma_f32_16x16x32_bf16(af[i], bfr[j], acc[i][j], 0, 0, 0);
        __syncthreads();
    }

    #pragma unroll
    for (int i = 0; i < 2; ++i) {
        int row = bm + wm + i * 16 + quad * 4;
        #pragma unroll
        for (int j = 0; j < 4; ++j) {
            int col = bn + wn + j * 16 + l15;
            float bia = bias[col];
            #pragma unroll
            for (int r = 0; r < 4; ++r) {
                size_t idx = (size_t)(row + r) * N + col;
                C[idx] = acc[i][j][r] + bia + res[idx];
            }
        }
    }
}

// ---------------- routing top-k ----------------
__global__ __launch_bounds__(64) void route_k(const float* __restrict__ qkwin,
                                              int* __restrict__ ridx) {
    int w = blockIdx.x;
    int n = w / 49;
    int tid = threadIdx.x;
    __shared__ float qv[256];
    __shared__ float lg[49];
    for (int i = tid; i < 256; i += 64) qv[i] = qkwin[(size_t)w * 512 + i] * ATT_SCALE;
    __syncthreads();
    if (tid < 49) {
        const float* kp = qkwin + (size_t)(n * 49 + tid) * 512 + 256;
        float d = 0.f;
        for (int cc = 0; cc < 256; ++cc) d += qv[cc] * kp[cc];
        lg[tid] = d;
    }
    __syncthreads();
    if (tid == 0) {
        #pragma unroll
        for (int t = 0; t < 4; ++t) {
            float best = -1e30f; int bi = 0;
            for (int j = 0; j < 49; ++j)
                if (lg[j] > best) { best = lg[j]; bi = j; }
            lg[bi] = -1e30f;
            ridx[w * 4 + t] = bi;
        }
    }
}

// ---------------- MFMA attention: block = (window, head), 4 waves x 16 queries ----------------
__global__ __launch_bounds__(256) void attn_mfma_k(const short* __restrict__ qkv,
                                                   const int* __restrict__ ridx,
                                                   short* __restrict__ attn) {
    const int blk = blockIdx.x;
    const int w = blk >> 3, h = blk & 7;
    const int n = w / 49;
    const int tid = threadIdx.x;
    const int wave = tid >> 6, lane = tid & 63;
    const int l15 = lane & 15, quad = lane >> 4;

    __shared__ __align__(16) short Ks[256 * 40];
    __shared__ __align__(16) short Vt[32 * 264];
    __shared__ __align__(16) short Ps[4 * 16 * 264];
    __shared__ int rs4[4];
    if (tid < 4) rs4[tid] = ridx[w * 4 + tid];
    __syncthreads();

    {
        int s = tid >> 2, kq = (tid & 3) * 8;
        #pragma unroll
        for (int u = 0; u < 4; ++u) {
            int key = u * 64 + s;
            const short* src = qkv + ((size_t)(n * 49 + rs4[u]) * 64 + s) * 768 + 256 + h * 32 + kq;
            *(short8*)&Ks[key * 40 + kq] = *(const short8*)src;
        }
    }
    {
        int key = tid;
        int t = key >> 6, s = key & 63;
        const short* src = qkv + ((size_t)(n * 49 + rs4[t]) * 64 + s) * 768 + 512 + h * 32;
        #pragma unroll
        for (int u = 0; u < 4; ++u) {
            short8 v = *(const short8*)(src + u * 8);
            #pragma unroll
            for (int i = 0; i < 8; ++i)
                Vt[(u * 8 + i) * 264 + key] = v[i];
        }
    }
    __syncthreads();

    const short* qp = qkv + ((size_t)w * 64 + wave * 16 + l15) * 768 + h * 32 + quad * 8;
    short8 qf = *(const short8*)qp;

    f32x4 st[16];
    #pragma unroll
    for (int j = 0; j < 16; ++j) {
        short8 kf = *(const short8*)&Ks[(j * 16 + l15) * 40 + quad * 8];
        st[j] = __builtin_amdgcn_mfma_f32_16x16x32_bf16(qf, kf, (f32x4){0.f, 0.f, 0.f, 0.f}, 0, 0, 0);
    }

    float lr[4];
    short* pw = &Ps[wave * 16 * 264];
    #pragma unroll
    for (int r = 0; r < 4; ++r) {
        float mx = -1e30f;
        #pragma unroll
        for (int j = 0; j < 16; ++j) mx = fmaxf(mx, st[j][r]);
        #pragma unroll
        for (int off = 1; off < 16; off <<= 1) mx = fmaxf(mx, __shfl_xor(mx, off));
        float sum = 0.f;
        #pragma unroll
        for (int j = 0; j < 16; ++j) {
            float p = __expf((st[j][r] - mx) * ATT_SCALE);
            sum += p;
            pw[(quad * 4 + r) * 264 + j * 16 + l15] = f2bs(p);
        }
        #pragma unroll
        for (int off = 1; off < 16; off <<= 1) sum += __shfl_xor(sum, off);
        lr[r] = sum;
    }
    __syncthreads();

    f32x4 oc[2] = {(f32x4){0.f,0.f,0.f,0.f}, (f32x4){0.f,0.f,0.f,0.f}};
    #pragma unroll
    for (int kk = 0; kk < 8; ++kk) {
        short8 pf = *(const short8*)&pw[l15 * 264 + kk * 32 + quad * 8];
        #pragma unroll
        for (int jj = 0; jj < 2; ++jj) {
            short8 vf = *(const short8*)&Vt[(jj * 16 + l15) * 264 + kk * 32 + quad * 8];
            oc[jj] = __builtin_amdgcn_mfma_f32_16x16x32_bf16(pf, vf, oc[jj], 0, 0, 0);
        }
    }

    short* op = attn + ((size_t)w * 64 + wave * 16) * 256 + h * 32;
    #pragma unroll
    for (int jj = 0; jj < 2; ++jj)
        #pragma unroll
        for (int r = 0; r < 4; ++r)
            op[(size_t)(quad * 4 + r) * 256 + jj * 16 + l15] = f2bs(oc[jj][r] / lr[r]);
}

// ---------------- LePE 5x5 dwconv + combine (vectorized 8-ch per thread) ----------------
__global__ __launch_bounds__(256) void lepe_k(const short* __restrict__ qkv,
                                              const short* __restrict__ attn,
                                              const float* __restrict__ lw,
                                              const float* __restrict__ lb,
                                              short* __restrict__ ywo) {
    int t = blockIdx.x * 8 + (threadIdx.x >> 5);
    int c0 = (threadIdx.x & 31) * 8;
    int n = t / 3136, rem = t % 3136, y = rem / 56, x = rem % 56;
    float sum[8];
    {
        float4 b0 = *(const float4*)(lb + c0), b1 = *(const float4*)(lb + c0 + 4);
        sum[0] = b0.x; sum[1] = b0.y; sum[2] = b0.z; sum[3] = b0.w;
        sum[4] = b1.x; sum[5] = b1.y; sum[6] = b1.z; sum[7] = b1.w;
    }
    #pragma unroll
    for (int ky = 0; ky < 5; ++ky) {
        int yy = y + ky - 2;
        if ((unsigned)yy >= 56u) continue;
        #pragma unroll
        for (int kx = 0; kx < 5; ++kx) {
            int xx = x + kx - 2;
            if ((unsigned)xx >= 56u) continue;
            int p = (yy >> 3) * 7 + (xx >> 3);
            int si = (yy & 7) * 8 + (xx & 7);
            short8 v = *(const short8*)(qkv + ((size_t)(n * 49 + p) * 64 + si) * 768 + 512 + c0);
            const float* wp = lw + (ky * 5 + kx) * 256 + c0;
            float4 w0 = *(const float4*)wp, w1 = *(const float4*)(wp + 4);
            sum[0] += bs2f(v[0]) * w0.x; sum[1] += bs2f(v[1]) * w0.y;
            sum[2] += bs2f(v[2]) * w0.z; sum[3] += bs2f(v[3]) * w0.w;
            sum[4] += bs2f(v[4]) * w1.x; sum[5] += bs2f(v[5]) * w1.y;
            sum[6] += bs2f(v[6]) * w1.z; sum[7] += bs2f(v[7]) * w1.w;
        }
    }
    int p0 = (y >> 3) * 7 + (x >> 3);
    int s0 = (y & 7) * 8 + (x & 7);
    short8 a = *(const short8*)(attn + ((size_t)(n * 49 + p0) * 64 + s0) * 256 + c0);
    short8 o;
    #pragma unroll
    for (int i = 0; i < 8; ++i) o[i] = f2bs(sum[i] + bs2f(a[i]));
    *(short8*)(ywo + (size_t)t * 256 + c0) = o;
}

extern "C" void kernel_launch(void* const* d_in, const int* in_sizes, int n_in,
                              void* d_out, int out_size, void* d_ws, size_t ws_size,
                              hipStream_t stream) {
    const float* x      = (const float*)d_in[0];
    const float* ln1_g  = (const float*)d_in[1];
    const float* ln1_b  = (const float*)d_in[2];
    const float* qkv_w  = (const float*)d_in[3];
    const float* qkv_b  = (const float*)d_in[4];
    const float* lepe_w = (const float*)d_in[5];
    const float* lepe_b = (const float*)d_in[6];
    const float* wo_w   = (const float*)d_in[7];
    const float* wo_b   = (const float*)d_in[8];
    const float* ln2_g  = (const float*)d_in[9];
    const float* ln2_b  = (const float*)d_in[10];
    const float* mlp_w1 = (const float*)d_in[11];
    const float* mlp_b1 = (const float*)d_in[12];
    const float* mlp_w2 = (const float*)d_in[13];
    const float* mlp_b2 = (const float*)d_in[14];
    float* out = (float*)d_out;

    char* ws = (char*)d_ws;
    __hip_bfloat16* wqkvT = (__hip_bfloat16*)(ws + OFF_WQKV);
    __hip_bfloat16* wwoT  = (__hip_bfloat16*)(ws + OFF_WWO);
    __hip_bfloat16* w1T   = (__hip_bfloat16*)(ws + OFF_W1);
    __hip_bfloat16* w2T   = (__hip_bfloat16*)(ws + OFF_W2);
    short* xln   = (short*)(ws + OFF_XLN);
    short* qkvb  = (short*)(ws + OFF_QKV);
    float* qkwin = (float*)(ws + OFF_QKWIN);
    int*   ridx  = (int*)(ws + OFF_RIDX);
    short* attnb = (short*)(ws + OFF_ATTN);
    short* ywo   = (short*)(ws + OFF_XLN);    // reuse
    short* h2    = (short*)(ws + OFF_ATTN);   // reuse
    short* hmid  = (short*)(ws + OFF_HMID);   // reuse XLN+QKV span

    // 0. all weights -> bf16 transposed (N x K), one launch
    transpose_cast4_k<<<768, 256, 0, stream>>>(qkv_w, wo_w, mlp_w1, mlp_w2,
                                               wqkvT, wwoT, w1T, w2T);
    // 1. LN1 -> xln bf16 (window order)
    ln_bf_k<<<TOK/4, 256, 0, stream>>>(x, ln1_g, ln1_b, xln, 1);
    // 2. qkv GEMM -> bf16, with fused window means
    gemm97<0, true><<<dim3(6, 196), 256, 0, stream>>>(xln, (const short*)wqkvT,
                                                      qkv_b, qkvb, qkwin, TOK, 768, 256);
    // 3. routing
    route_k<<<NPW, 64, 0, stream>>>(qkwin, ridx);
    // 4. attention (MFMA) -> bf16
    attn_mfma_k<<<NPW * 8, 256, 0, stream>>>(qkvb, ridx, attnb);
    // 5. lepe + combine -> ywo bf16 (image order)
    lepe_k<<<TOK/8, 256, 0, stream>>>(qkvb, attnb, lepe_w, lepe_b, ywo);
    // 6. wo GEMM + x residual -> d_out f32 (64x128 tiles)
    gemm_s<<<dim3(2, 392), 256, 0, stream>>>(ywo, (const short*)wwoT,
                                             wo_b, x, out, TOK, 256, 256);
    // 7. LN2 -> h2 bf16
    ln_bf_k<<<TOK/4, 256, 0, stream>>>(out, ln2_g, ln2_b, h2, 0);
    // 8. MLP1 GEMM + gelu -> hmid bf16
    gemm97<2, false><<<dim3(8, 196), 256, 0, stream>>>(h2, (const short*)w1T,
                                                       mlp_b1, hmid, nullptr, TOK, 1024, 256);
    // 9. MLP2 GEMM + bias + residual -> d_out f32 (64x128 tiles)
    gemm_s<<<dim3(2, 392), 256, 0, stream>>>(hmid, (const short*)w2T,
                                             mlp_b2, out, out, TOK, 256, 1024);
}

// Round 10
// 313.059 us; speedup vs baseline: 1.1005x; 1.0182x over previous
//
#include <hip/hip_runtime.h>
#include <hip/hip_bf16.h>

#define NIMG 8
#define HW 56
#define CDIM 256
#define TOK (NIMG*HW*HW)        // 25088
#define NWIN 49
#define NPW (NIMG*NWIN)         // 392
#define ATT_SCALE 0.0625f       // 256^-0.5

typedef __attribute__((ext_vector_type(8))) short short8;
typedef __attribute__((ext_vector_type(4))) short short4v;
typedef __attribute__((ext_vector_type(4))) float f32x4;

// ---- workspace layout (bytes, 16B aligned) ----
static const size_t OFF_WQKV  = 0;           // 768x256 bf16
static const size_t OFF_WWO   = 393216;      // 256x256 bf16
static const size_t OFF_W1    = 524288;      // 1024x256 bf16
static const size_t OFF_W2    = 1048576;     // 256x1024 bf16
static const size_t OFF_XLN   = 1572864;     // 25088x256 bf16 (reused: ywo)
static const size_t OFF_QKV   = 14417920;    // 25088x768 bf16
static const size_t OFF_QKWIN = 52953088;    // 392x512 f32
static const size_t OFF_RIDX  = 53755904;    // 392x4 int
static const size_t OFF_ATTN  = 53762176;    // 25088x256 bf16 (reused: h2)
static const size_t OFF_HMID  = OFF_XLN;     // 25088x1024 bf16 spans XLN+QKV regions

__device__ __forceinline__ float gelu_exact(float v) {
    return 0.5f * v * (1.f + erff(v * 0.70710678118654752f));
}
__device__ __forceinline__ short f2bs(float x) {
    __hip_bfloat16 h = __float2bfloat16(x);
    return *(short*)&h;
}
__device__ __forceinline__ float bs2f(short s) {
    return __uint_as_float(((unsigned)(unsigned short)s) << 16);
}
// async global->LDS, 16B per lane; LDS dest is wave-uniform base + lane*16
__device__ __forceinline__ void gld16(const short* g, short* l) {
    __builtin_amdgcn_global_load_lds(
        (const __attribute__((address_space(1))) void*)g,
        (__attribute__((address_space(3))) void*)l, 16, 0, 0);
}

// ---------------- batched weight transpose+cast: 4 weights in one launch ----------------
__global__ __launch_bounds__(256) void transpose_cast4_k(const float* __restrict__ s0,
                                                         const float* __restrict__ s1,
                                                         const float* __restrict__ s2,
                                                         const float* __restrict__ s3,
                                                         __hip_bfloat16* __restrict__ d0,
                                                         __hip_bfloat16* __restrict__ d1,
                                                         __hip_bfloat16* __restrict__ d2,
                                                         __hip_bfloat16* __restrict__ d3) {
    int b = blockIdx.x;
    const float* src; __hip_bfloat16* dst; int K, N, l;
    if (b < 192)      { src = s0; dst = d0; K = 256;  N = 768;  l = b; }
    else if (b < 256) { src = s1; dst = d1; K = 256;  N = 256;  l = b - 192; }
    else if (b < 512) { src = s2; dst = d2; K = 256;  N = 1024; l = b - 256; }
    else              { src = s3; dst = d3; K = 1024; N = 256;  l = b - 512; }
    int nx = N / 32;
    int n0 = (l % nx) * 32, k0 = (l / nx) * 32;
    __shared__ float t[32][33];
    int tx = threadIdx.x & 31, ty = threadIdx.x >> 5;   // 32 x 8
    #pragma unroll
    for (int i = 0; i < 32; i += 8)
        t[ty + i][tx] = src[(size_t)(k0 + ty + i) * N + n0 + tx];
    __syncthreads();
    #pragma unroll
    for (int i = 0; i < 32; i += 8)
        dst[(size_t)(n0 + ty + i) * K + k0 + tx] = __float2bfloat16(t[tx][ty + i]);
}

// ---------------- LayerNorm: wave per token, lane = 4 channels ----------------
__global__ __launch_bounds__(256) void ln_bf_k(const float* __restrict__ in,
                                               const float* __restrict__ g,
                                               const float* __restrict__ b,
                                               short* __restrict__ out, int remap) {
    int t = blockIdx.x * 4 + (threadIdx.x >> 6);
    int lane = threadIdx.x & 63;
    float4 v = *(const float4*)(in + (size_t)t * 256 + lane * 4);
    float s = v.x + v.y + v.z + v.w;
    float s2 = v.x * v.x + v.y * v.y + v.z * v.z + v.w * v.w;
    #pragma unroll
    for (int o = 32; o > 0; o >>= 1) {
        s  += __shfl_xor(s, o);
        s2 += __shfl_xor(s2, o);
    }
    float mu = s * (1.f / 256.f);
    float rstd = rsqrtf(s2 * (1.f / 256.f) - mu * mu + 1e-6f);
    float4 gv = *(const float4*)(g + lane * 4);
    float4 bv = *(const float4*)(b + lane * 4);
    short4v o;
    o[0] = f2bs((v.x - mu) * rstd * gv.x + bv.x);
    o[1] = f2bs((v.y - mu) * rstd * gv.y + bv.y);
    o[2] = f2bs((v.z - mu) * rstd * gv.z + bv.z);
    o[3] = f2bs((v.w - mu) * rstd * gv.w + bv.w);
    size_t tb;
    if (remap) {
        int n = t / 3136, rem = t % 3136, y = rem / 56, x = rem % 56;
        int p = (y >> 3) * 7 + (x >> 3);
        int si = (y & 7) * 8 + (x & 7);
        tb = (size_t)(n * 49 + p) * 64 + si;
    } else {
        tb = (size_t)t;
    }
    *(short4v*)(out + tb * 256 + lane * 4) = o;
}

// ---------------- unified 64Mx128N bf16 MFMA GEMM, BK=32, global_load_lds ----------------
// MODE 0: bf16 out +bias (LDS-transpose epilogue)
// MODE 1: f32 out +bias+res (direct stores)
// MODE 2: bf16 out gelu(+bias) (LDS-transpose epilogue)
template<int MODE>
__global__ __launch_bounds__(256) void gemm64(const short* __restrict__ A,
                                              const short* __restrict__ Bt,
                                              const float* __restrict__ bias,
                                              const float* __restrict__ res,
                                              void* Cv, int M, int N, int K) {
    const int bn = blockIdx.x * 128;
    const int bm = blockIdx.y * 64;
    const int tid = threadIdx.x;
    const int wave = tid >> 6, lane = tid & 63;
    const int l15 = lane & 15, quad = lane >> 4;
    const int wm = (wave & 1) * 32, wn = (wave >> 1) * 64;

    __shared__ __align__(16) short smem[6144];   // As 2048 | Bs 4096 (12KB)
    short* As = smem;
    short* Bs = smem + 2048;

    f32x4 acc[2][4];
    #pragma unroll
    for (int i = 0; i < 2; ++i)
        #pragma unroll
        for (int j = 0; j < 4; ++j) acc[i][j] = (f32x4){0.f, 0.f, 0.f, 0.f};

    const int crow = lane >> 2;          // 0..15
    const int ckq = (lane & 3) * 8;
    const short* ga  = A  + (size_t)(bm + wave * 16 + crow) * K + ckq;
    const short* gb0 = Bt + (size_t)(bn + wave * 16 + crow) * K + ckq;
    const short* gb1 = gb0 + (size_t)64 * K;
    // each wave's gld16 covers 64 lanes x 16B = 512 shorts = 16 rows
    short* la  = As + wave * 512;
    short* lb0 = Bs + wave * 512;
    short* lb1 = Bs + 2048 + wave * 512;

    for (int k0 = 0; k0 < K; k0 += 32) {
        gld16(ga + k0, la);
        gld16(gb0 + k0, lb0);
        gld16(gb1 + k0, lb1);
        __syncthreads();   // barrier drains the DMA (compiler emits vmcnt(0) before s_barrier)
        short8 af[2], bfr[4];
        #pragma unroll
        for (int i = 0; i < 2; ++i)
            af[i] = *(const short8*)&As[(wm + i * 16 + l15) * 32 + quad * 8];
        #pragma unroll
        for (int j = 0; j < 4; ++j)
            bfr[j] = *(const short8*)&Bs[(wn + j * 16 + l15) * 32 + quad * 8];
        #pragma unroll
        for (int i = 0; i < 2; ++i)
            #pragma unroll
            for (int j = 0; j < 4; ++j)
                acc[i][j] = __builtin_amdgcn_mfma_f32_16x16x32_bf16(af[i], bfr[j], acc[i][j], 0, 0, 0);
        __syncthreads();   // reads done before next iter's DMA overwrites
    }

    if (MODE == 1) {
        // direct f32 stores +bias+res
        #pragma unroll
        for (int i = 0; i < 2; ++i) {
            int row = bm + wm + i * 16 + quad * 4;
            #pragma unroll
            for (int j = 0; j < 4; ++j) {
                int col = bn + wn + j * 16 + l15;
                float bia = bias[col];
                #pragma unroll
                for (int r = 0; r < 4; ++r) {
                    size_t idx = (size_t)(row + r) * N + col;
                    ((float*)Cv)[idx] = acc[i][j][r] + bia + res[idx];
                }
            }
        }
    } else {
        // bf16 out via per-wave LDS transpose: region = 32 rows x 40 stride = 1280 shorts
        float biasv[4];
        #pragma unroll
        for (int j = 0; j < 4; ++j) biasv[j] = bias[bn + wn + j * 16 + l15];
        short* ep = &smem[wave * 1280];
        short* outp = (short*)Cv;
        #pragma unroll
        for (int p = 0; p < 2; ++p) {       // halves of the 64-col wave span
            #pragma unroll
            for (int i = 0; i < 2; ++i)
                #pragma unroll
                for (int jj = 0; jj < 2; ++jj) {
                    int j = p * 2 + jj;
                    #pragma unroll
                    for (int r = 0; r < 4; ++r) {
                        float v = acc[i][j][r] + biasv[j];
                        if (MODE == 2) v = gelu_exact(v);
                        ep[(i * 16 + quad * 4 + r) * 40 + jj * 16 + l15] = f2bs(v);
                    }
                }
            __builtin_amdgcn_s_waitcnt(0);   // wave-local drain of LDS writes
            int c = lane & 3;
            #pragma unroll
            for (int rr = 0; rr < 2; ++rr) {
                int row = rr * 16 + (lane >> 2);
                short8 v = *(const short8*)&ep[row * 40 + c * 8];
                *(short8*)&outp[(size_t)(bm + wm + row) * N + bn + wn + p * 32 + c * 8] = v;
            }
            __builtin_amdgcn_s_waitcnt(0);   // drain reads before next pass overwrites
        }
    }
}

// ---------------- window means of q,k: block per window, short8 loads ----------------
__global__ __launch_bounds__(256) void win_means_k(const short* __restrict__ qkv,
                                                   float* __restrict__ qkwin) {
    int w = blockIdx.x;
    int cg = (threadIdx.x & 63) * 8;
    int sp = threadIdx.x >> 6;
    float s[8] = {0.f, 0.f, 0.f, 0.f, 0.f, 0.f, 0.f, 0.f};
    const short* base = qkv + (size_t)w * 64 * 768 + cg;
    for (int si = sp; si < 64; si += 4) {
        short8 v = *(const short8*)(base + (size_t)si * 768);
        #pragma unroll
        for (int i = 0; i < 8; ++i) s[i] += bs2f(v[i]);
    }
    __shared__ float red[4][512];
    #pragma unroll
    for (int i = 0; i < 8; ++i) red[sp][cg + i] = s[i];
    __syncthreads();
    for (int c = threadIdx.x; c < 512; c += 256) {
        float t = red[0][c] + red[1][c] + red[2][c] + red[3][c];
        qkwin[(size_t)w * 512 + c] = t * (1.f / 64.f);
    }
}

// ---------------- routing top-k ----------------
__global__ __launch_bounds__(64) void route_k(const float* __restrict__ qkwin,
                                              int* __restrict__ ridx) {
    int w = blockIdx.x;
    int n = w / 49;
    int tid = threadIdx.x;
    __shared__ float qv[256];
    __shared__ float lg[49];
    for (int i = tid; i < 256; i += 64) qv[i] = qkwin[(size_t)w * 512 + i] * ATT_SCALE;
    __syncthreads();
    if (tid < 49) {
        const float* kp = qkwin + (size_t)(n * 49 + tid) * 512 + 256;
        float d = 0.f;
        for (int cc = 0; cc < 256; ++cc) d += qv[cc] * kp[cc];
        lg[tid] = d;
    }
    __syncthreads();
    if (tid == 0) {
        #pragma unroll
        for (int t = 0; t < 4; ++t) {
            float best = -1e30f; int bi = 0;
            for (int j = 0; j < 49; ++j)
                if (lg[j] > best) { best = lg[j]; bi = j; }
            lg[bi] = -1e30f;
            ridx[w * 4 + t] = bi;
        }
    }
}

// ---------------- MFMA attention: block = (window, head), 4 waves x 16 queries ----------------
__global__ __launch_bounds__(256) void attn_mfma_k(const short* __restrict__ qkv,
                                                   const int* __restrict__ ridx,
                                                   short* __restrict__ attn) {
    const int blk = blockIdx.x;
    const int w = blk >> 3, h = blk & 7;
    const int n = w / 49;
    const int tid = threadIdx.x;
    const int wave = tid >> 6, lane = tid & 63;
    const int l15 = lane & 15, quad = lane >> 4;

    __shared__ __align__(16) short Ks[256 * 40];
    __shared__ __align__(16) short Vt[32 * 264];
    __shared__ __align__(16) short Ps[4 * 16 * 264];
    __shared__ int rs4[4];
    if (tid < 4) rs4[tid] = ridx[w * 4 + tid];
    __syncthreads();

    {
        int s = tid >> 2, kq = (tid & 3) * 8;
        #pragma unroll
        for (int u = 0; u < 4; ++u) {
            int key = u * 64 + s;
            const short* src = qkv + ((size_t)(n * 49 + rs4[u]) * 64 + s) * 768 + 256 + h * 32 + kq;
            *(short8*)&Ks[key * 40 + kq] = *(const short8*)src;
        }
    }
    {
        int key = tid;
        int t = key >> 6, s = key & 63;
        const short* src = qkv + ((size_t)(n * 49 + rs4[t]) * 64 + s) * 768 + 512 + h * 32;
        #pragma unroll
        for (int u = 0; u < 4; ++u) {
            short8 v = *(const short8*)(src + u * 8);
            #pragma unroll
            for (int i = 0; i < 8; ++i)
                Vt[(u * 8 + i) * 264 + key] = v[i];
        }
    }
    __syncthreads();

    const short* qp = qkv + ((size_t)w * 64 + wave * 16 + l15) * 768 + h * 32 + quad * 8;
    short8 qf = *(const short8*)qp;

    f32x4 st[16];
    #pragma unroll
    for (int j = 0; j < 16; ++j) {
        short8 kf = *(const short8*)&Ks[(j * 16 + l15) * 40 + quad * 8];
        st[j] = __builtin_amdgcn_mfma_f32_16x16x32_bf16(qf, kf, (f32x4){0.f, 0.f, 0.f, 0.f}, 0, 0, 0);
    }

    float lr[4];
    short* pw = &Ps[wave * 16 * 264];
    #pragma unroll
    for (int r = 0; r < 4; ++r) {
        float mx = -1e30f;
        #pragma unroll
        for (int j = 0; j < 16; ++j) mx = fmaxf(mx, st[j][r]);
        #pragma unroll
        for (int off = 1; off < 16; off <<= 1) mx = fmaxf(mx, __shfl_xor(mx, off));
        float sum = 0.f;
        #pragma unroll
        for (int j = 0; j < 16; ++j) {
            float p = __expf((st[j][r] - mx) * ATT_SCALE);
            sum += p;
            pw[(quad * 4 + r) * 264 + j * 16 + l15] = f2bs(p);
        }
        #pragma unroll
        for (int off = 1; off < 16; off <<= 1) sum += __shfl_xor(sum, off);
        lr[r] = sum;
    }
    __syncthreads();

    f32x4 oc[2] = {(f32x4){0.f,0.f,0.f,0.f}, (f32x4){0.f,0.f,0.f,0.f}};
    #pragma unroll
    for (int kk = 0; kk < 8; ++kk) {
        short8 pf = *(const short8*)&pw[l15 * 264 + kk * 32 + quad * 8];
        #pragma unroll
        for (int jj = 0; jj < 2; ++jj) {
            short8 vf = *(const short8*)&Vt[(jj * 16 + l15) * 264 + kk * 32 + quad * 8];
            oc[jj] = __builtin_amdgcn_mfma_f32_16x16x32_bf16(pf, vf, oc[jj], 0, 0, 0);
        }
    }

    short* op = attn + ((size_t)w * 64 + wave * 16) * 256 + h * 32;
    #pragma unroll
    for (int jj = 0; jj < 2; ++jj)
        #pragma unroll
        for (int r = 0; r < 4; ++r)
            op[(size_t)(quad * 4 + r) * 256 + jj * 16 + l15] = f2bs(oc[jj][r] / lr[r]);
}

// ---------------- LePE 5x5 dwconv + combine (vectorized 8-ch per thread) ----------------
__global__ __launch_bounds__(256) void lepe_k(const short* __restrict__ qkv,
                                              const short* __restrict__ attn,
                                              const float* __restrict__ lw,
                                              const float* __restrict__ lb,
                                              short* __restrict__ ywo) {
    int t = blockIdx.x * 8 + (threadIdx.x >> 5);
    int c0 = (threadIdx.x & 31) * 8;
    int n = t / 3136, rem = t % 3136, y = rem / 56, x = rem % 56;
    float sum[8];
    {
        float4 b0 = *(const float4*)(lb + c0), b1 = *(const float4*)(lb + c0 + 4);
        sum[0] = b0.x; sum[1] = b0.y; sum[2] = b0.z; sum[3] = b0.w;
        sum[4] = b1.x; sum[5] = b1.y; sum[6] = b1.z; sum[7] = b1.w;
    }
    #pragma unroll
    for (int ky = 0; ky < 5; ++ky) {
        int yy = y + ky - 2;
        if ((unsigned)yy >= 56u) continue;
        #pragma unroll
        for (int kx = 0; kx < 5; ++kx) {
            int xx = x + kx - 2;
            if ((unsigned)xx >= 56u) continue;
            int p = (yy >> 3) * 7 + (xx >> 3);
            int si = (yy & 7) * 8 + (xx & 7);
            short8 v = *(const short8*)(qkv + ((size_t)(n * 49 + p) * 64 + si) * 768 + 512 + c0);
            const float* wp = lw + (ky * 5 + kx) * 256 + c0;
            float4 w0 = *(const float4*)wp, w1 = *(const float4*)(wp + 4);
            sum[0] += bs2f(v[0]) * w0.x; sum[1] += bs2f(v[1]) * w0.y;
            sum[2] += bs2f(v[2]) * w0.z; sum[3] += bs2f(v[3]) * w0.w;
            sum[4] += bs2f(v[4]) * w1.x; sum[5] += bs2f(v[5]) * w1.y;
            sum[6] += bs2f(v[6]) * w1.z; sum[7] += bs2f(v[7]) * w1.w;
        }
    }
    int p0 = (y >> 3) * 7 + (x >> 3);
    int s0 = (y & 7) * 8 + (x & 7);
    short8 a = *(const short8*)(attn + ((size_t)(n * 49 + p0) * 64 + s0) * 256 + c0);
    short8 o;
    #pragma unroll
    for (int i = 0; i < 8; ++i) o[i] = f2bs(sum[i] + bs2f(a[i]));
    *(short8*)(ywo + (size_t)t * 256 + c0) = o;
}

extern "C" void kernel_launch(void* const* d_in, const int* in_sizes, int n_in,
                              void* d_out, int out_size, void* d_ws, size_t ws_size,
                              hipStream_t stream) {
    const float* x      = (const float*)d_in[0];
    const float* ln1_g  = (const float*)d_in[1];
    const float* ln1_b  = (const float*)d_in[2];
    const float* qkv_w  = (const float*)d_in[3];
    const float* qkv_b  = (const float*)d_in[4];
    const float* lepe_w = (const float*)d_in[5];
    const float* lepe_b = (const float*)d_in[6];
    const float* wo_w   = (const float*)d_in[7];
    const float* wo_b   = (const float*)d_in[8];
    const float* ln2_g  = (const float*)d_in[9];
    const float* ln2_b  = (const float*)d_in[10];
    const float* mlp_w1 = (const float*)d_in[11];
    const float* mlp_b1 = (const float*)d_in[12];
    const float* mlp_w2 = (const float*)d_in[13];
    const float* mlp_b2 = (const float*)d_in[14];
    float* out = (float*)d_out;

    char* ws = (char*)d_ws;
    __hip_bfloat16* wqkvT = (__hip_bfloat16*)(ws + OFF_WQKV);
    __hip_bfloat16* wwoT  = (__hip_bfloat16*)(ws + OFF_WWO);
    __hip_bfloat16* w1T   = (__hip_bfloat16*)(ws + OFF_W1);
    __hip_bfloat16* w2T   = (__hip_bfloat16*)(ws + OFF_W2);
    short* xln   = (short*)(ws + OFF_XLN);
    short* qkvb  = (short*)(ws + OFF_QKV);
    float* qkwin = (float*)(ws + OFF_QKWIN);
    int*   ridx  = (int*)(ws + OFF_RIDX);
    short* attnb = (short*)(ws + OFF_ATTN);
    short* ywo   = (short*)(ws + OFF_XLN);    // reuse
    short* h2    = (short*)(ws + OFF_ATTN);   // reuse
    short* hmid  = (short*)(ws + OFF_HMID);   // reuse XLN+QKV span

    // 0. all weights -> bf16 transposed (N x K), one launch
    transpose_cast4_k<<<768, 256, 0, stream>>>(qkv_w, wo_w, mlp_w1, mlp_w2,
                                               wqkvT, wwoT, w1T, w2T);
    // 1. LN1 -> xln bf16 (window order)
    ln_bf_k<<<TOK/4, 256, 0, stream>>>(x, ln1_g, ln1_b, xln, 1);
    // 2. qkv GEMM -> bf16
    gemm64<0><<<dim3(6, 392), 256, 0, stream>>>(xln, (const short*)wqkvT,
                                                qkv_b, nullptr, qkvb, TOK, 768, 256);
    // 3. window means
    win_means_k<<<NPW, 256, 0, stream>>>(qkvb, qkwin);
    // 4. routing
    route_k<<<NPW, 64, 0, stream>>>(qkwin, ridx);
    // 5. attention (MFMA) -> bf16
    attn_mfma_k<<<NPW * 8, 256, 0, stream>>>(qkvb, ridx, attnb);
    // 6. lepe + combine -> ywo bf16 (image order)
    lepe_k<<<TOK/8, 256, 0, stream>>>(qkvb, attnb, lepe_w, lepe_b, ywo);
    // 7. wo GEMM + x residual -> d_out f32
    gemm64<1><<<dim3(2, 392), 256, 0, stream>>>(ywo, (const short*)wwoT,
                                                wo_b, x, out, TOK, 256, 256);
    // 8. LN2 -> h2 bf16
    ln_bf_k<<<TOK/4, 256, 0, stream>>>(out, ln2_g, ln2_b, h2, 0);
    // 9. MLP1 GEMM + gelu -> hmid bf16
    gemm64<2><<<dim3(8, 392), 256, 0, stream>>>(h2, (const short*)w1T,
                                                mlp_b1, nullptr, hmid, TOK, 1024, 256);
    // 10. MLP2 GEMM + bias + residual -> d_out f32
    gemm64<1><<<dim3(2, 392), 256, 0, stream>>>(hmid, (const short*)w2T,
                                                mlp_b2, out, out, TOK, 256, 1024);
}

// Round 11
// 299.809 us; speedup vs baseline: 1.1491x; 1.0442x over previous
//
#include <hip/hip_runtime.h>
#include <hip/hip_bf16.h>

#define NIMG 8
#define HW 56
#define CDIM 256
#define TOK (NIMG*HW*HW)        // 25088
#define NWIN 49
#define NPW (NIMG*NWIN)         // 392
#define ATT_SCALE 0.0625f       // 256^-0.5

typedef __attribute__((ext_vector_type(8))) short short8;
typedef __attribute__((ext_vector_type(4))) short short4v;
typedef __attribute__((ext_vector_type(4))) float f32x4;

// ---- workspace layout (bytes, 16B aligned) ----
static const size_t OFF_WQKV  = 0;           // 768x256 bf16
static const size_t OFF_WWO   = 393216;      // 256x256 bf16
static const size_t OFF_W1    = 524288;      // 1024x256 bf16
static const size_t OFF_W2    = 1048576;     // 256x1024 bf16
static const size_t OFF_XLN   = 1572864;     // 25088x256 bf16 (reused: ywo)
static const size_t OFF_QKV   = 14417920;    // 25088x768 bf16
static const size_t OFF_QKWIN = 52953088;    // 392x512 f32
static const size_t OFF_RIDX  = 53755904;    // 392x4 int
static const size_t OFF_ATTN  = 53762176;    // 25088x256 bf16 (reused: h2)
static const size_t OFF_HMID  = OFF_XLN;     // 25088x1024 bf16 spans XLN+QKV regions

__device__ __forceinline__ float gelu_exact(float v) {
    return 0.5f * v * (1.f + erff(v * 0.70710678118654752f));
}
__device__ __forceinline__ short f2bs(float x) {
    __hip_bfloat16 h = __float2bfloat16(x);
    return *(short*)&h;
}
__device__ __forceinline__ float bs2f(short s) {
    return __uint_as_float(((unsigned)(unsigned short)s) << 16);
}
// async global->LDS, 16B per lane; LDS dest is wave-uniform base + lane*16
__device__ __forceinline__ void gld16(const short* g, short* l) {
    __builtin_amdgcn_global_load_lds(
        (const __attribute__((address_space(1))) void*)g,
        (__attribute__((address_space(3))) void*)l, 16, 0, 0);
}

// ---------------- batched weight transpose+cast: 4 weights in one launch ----------------
__global__ __launch_bounds__(256) void transpose_cast4_k(const float* __restrict__ s0,
                                                         const float* __restrict__ s1,
                                                         const float* __restrict__ s2,
                                                         const float* __restrict__ s3,
                                                         __hip_bfloat16* __restrict__ d0,
                                                         __hip_bfloat16* __restrict__ d1,
                                                         __hip_bfloat16* __restrict__ d2,
                                                         __hip_bfloat16* __restrict__ d3) {
    int b = blockIdx.x;
    const float* src; __hip_bfloat16* dst; int K, N, l;
    if (b < 192)      { src = s0; dst = d0; K = 256;  N = 768;  l = b; }
    else if (b < 256) { src = s1; dst = d1; K = 256;  N = 256;  l = b - 192; }
    else if (b < 512) { src = s2; dst = d2; K = 256;  N = 1024; l = b - 256; }
    else              { src = s3; dst = d3; K = 1024; N = 256;  l = b - 512; }
    int nx = N / 32;
    int n0 = (l % nx) * 32, k0 = (l / nx) * 32;
    __shared__ float t[32][33];
    int tx = threadIdx.x & 31, ty = threadIdx.x >> 5;   // 32 x 8
    #pragma unroll
    for (int i = 0; i < 32; i += 8)
        t[ty + i][tx] = src[(size_t)(k0 + ty + i) * N + n0 + tx];
    __syncthreads();
    #pragma unroll
    for (int i = 0; i < 32; i += 8)
        dst[(size_t)(n0 + ty + i) * K + k0 + tx] = __float2bfloat16(t[tx][ty + i]);
}

// ---------------- LayerNorm: wave per token, lane = 4 channels ----------------
__global__ __launch_bounds__(256) void ln_bf_k(const float* __restrict__ in,
                                               const float* __restrict__ g,
                                               const float* __restrict__ b,
                                               short* __restrict__ out, int remap) {
    int t = blockIdx.x * 4 + (threadIdx.x >> 6);
    int lane = threadIdx.x & 63;
    float4 v = *(const float4*)(in + (size_t)t * 256 + lane * 4);
    float s = v.x + v.y + v.z + v.w;
    float s2 = v.x * v.x + v.y * v.y + v.z * v.z + v.w * v.w;
    #pragma unroll
    for (int o = 32; o > 0; o >>= 1) {
        s  += __shfl_xor(s, o);
        s2 += __shfl_xor(s2, o);
    }
    float mu = s * (1.f / 256.f);
    float rstd = rsqrtf(s2 * (1.f / 256.f) - mu * mu + 1e-6f);
    float4 gv = *(const float4*)(g + lane * 4);
    float4 bv = *(const float4*)(b + lane * 4);
    short4v o;
    o[0] = f2bs((v.x - mu) * rstd * gv.x + bv.x);
    o[1] = f2bs((v.y - mu) * rstd * gv.y + bv.y);
    o[2] = f2bs((v.z - mu) * rstd * gv.z + bv.z);
    o[3] = f2bs((v.w - mu) * rstd * gv.w + bv.w);
    size_t tb;
    if (remap) {
        int n = t / 3136, rem = t % 3136, y = rem / 56, x = rem % 56;
        int p = (y >> 3) * 7 + (x >> 3);
        int si = (y & 7) * 8 + (x & 7);
        tb = (size_t)(n * 49 + p) * 64 + si;
    } else {
        tb = (size_t)t;
    }
    *(short4v*)(out + tb * 256 + lane * 4) = o;
}

// ---------------- unified 64Mx128N bf16 MFMA GEMM, BK=32, global_load_lds ----------------
// MODE 0: bf16 out +bias (LDS-transpose epilogue)
// MODE 1: f32 out +bias+res (direct stores)
// MODE 2: bf16 out gelu(+bias) (LDS-transpose epilogue)
template<int MODE>
__global__ __launch_bounds__(256) void gemm64(const short* __restrict__ A,
                                              const short* __restrict__ Bt,
                                              const float* __restrict__ bias,
                                              const float* __restrict__ res,
                                              void* Cv, int M, int N, int K) {
    const int bn = blockIdx.x * 128;
    const int bm = blockIdx.y * 64;
    const int tid = threadIdx.x;
    const int wave = tid >> 6, lane = tid & 63;
    const int l15 = lane & 15, quad = lane >> 4;
    const int wm = (wave & 1) * 32, wn = (wave >> 1) * 64;

    __shared__ __align__(16) short smem[6144];   // As 2048 | Bs 4096 (12KB)
    short* As = smem;
    short* Bs = smem + 2048;

    f32x4 acc[2][4];
    #pragma unroll
    for (int i = 0; i < 2; ++i)
        #pragma unroll
        for (int j = 0; j < 4; ++j) acc[i][j] = (f32x4){0.f, 0.f, 0.f, 0.f};

    const int crow = lane >> 2;          // 0..15
    const int ckq = (lane & 3) * 8;
    const short* ga  = A  + (size_t)(bm + wave * 16 + crow) * K + ckq;
    const short* gb0 = Bt + (size_t)(bn + wave * 16 + crow) * K + ckq;
    const short* gb1 = gb0 + (size_t)64 * K;
    short* la  = As + wave * 512;
    short* lb0 = Bs + wave * 512;
    short* lb1 = Bs + 2048 + wave * 512;

    for (int k0 = 0; k0 < K; k0 += 32) {
        gld16(ga + k0, la);
        gld16(gb0 + k0, lb0);
        gld16(gb1 + k0, lb1);
        __syncthreads();
        short8 af[2], bfr[4];
        #pragma unroll
        for (int i = 0; i < 2; ++i)
            af[i] = *(const short8*)&As[(wm + i * 16 + l15) * 32 + quad * 8];
        #pragma unroll
        for (int j = 0; j < 4; ++j)
            bfr[j] = *(const short8*)&Bs[(wn + j * 16 + l15) * 32 + quad * 8];
        #pragma unroll
        for (int i = 0; i < 2; ++i)
            #pragma unroll
            for (int j = 0; j < 4; ++j)
                acc[i][j] = __builtin_amdgcn_mfma_f32_16x16x32_bf16(af[i], bfr[j], acc[i][j], 0, 0, 0);
        __syncthreads();
    }

    if (MODE == 1) {
        #pragma unroll
        for (int i = 0; i < 2; ++i) {
            int row = bm + wm + i * 16 + quad * 4;
            #pragma unroll
            for (int j = 0; j < 4; ++j) {
                int col = bn + wn + j * 16 + l15;
                float bia = bias[col];
                #pragma unroll
                for (int r = 0; r < 4; ++r) {
                    size_t idx = (size_t)(row + r) * N + col;
                    ((float*)Cv)[idx] = acc[i][j][r] + bia + res[idx];
                }
            }
        }
    } else {
        float biasv[4];
        #pragma unroll
        for (int j = 0; j < 4; ++j) biasv[j] = bias[bn + wn + j * 16 + l15];
        short* ep = &smem[wave * 1280];
        short* outp = (short*)Cv;
        #pragma unroll
        for (int p = 0; p < 2; ++p) {
            #pragma unroll
            for (int i = 0; i < 2; ++i)
                #pragma unroll
                for (int jj = 0; jj < 2; ++jj) {
                    int j = p * 2 + jj;
                    #pragma unroll
                    for (int r = 0; r < 4; ++r) {
                        float v = acc[i][j][r] + biasv[j];
                        if (MODE == 2) v = gelu_exact(v);
                        ep[(i * 16 + quad * 4 + r) * 40 + jj * 16 + l15] = f2bs(v);
                    }
                }
            __builtin_amdgcn_s_waitcnt(0);
            int c = lane & 3;
            #pragma unroll
            for (int rr = 0; rr < 2; ++rr) {
                int row = rr * 16 + (lane >> 2);
                short8 v = *(const short8*)&ep[row * 40 + c * 8];
                *(short8*)&outp[(size_t)(bm + wm + row) * N + bn + wn + p * 32 + c * 8] = v;
            }
            __builtin_amdgcn_s_waitcnt(0);
        }
    }
}

// ---------------- window means of q,k: block per window, short8 loads ----------------
__global__ __launch_bounds__(256) void win_means_k(const short* __restrict__ qkv,
                                                   float* __restrict__ qkwin) {
    int w = blockIdx.x;
    int cg = (threadIdx.x & 63) * 8;
    int sp = threadIdx.x >> 6;
    float s[8] = {0.f, 0.f, 0.f, 0.f, 0.f, 0.f, 0.f, 0.f};
    const short* base = qkv + (size_t)w * 64 * 768 + cg;
    for (int si = sp; si < 64; si += 4) {
        short8 v = *(const short8*)(base + (size_t)si * 768);
        #pragma unroll
        for (int i = 0; i < 8; ++i) s[i] += bs2f(v[i]);
    }
    __shared__ float red[4][512];
    #pragma unroll
    for (int i = 0; i < 8; ++i) red[sp][cg + i] = s[i];
    __syncthreads();
    for (int c = threadIdx.x; c < 512; c += 256) {
        float t = red[0][c] + red[1][c] + red[2][c] + red[3][c];
        qkwin[(size_t)w * 512 + c] = t * (1.f / 64.f);
    }
}

// ---------------- routing top-k ----------------
__global__ __launch_bounds__(64) void route_k(const float* __restrict__ qkwin,
                                              int* __restrict__ ridx) {
    int w = blockIdx.x;
    int n = w / 49;
    int tid = threadIdx.x;
    __shared__ float qv[256];
    __shared__ float lg[49];
    for (int i = tid; i < 256; i += 64) qv[i] = qkwin[(size_t)w * 512 + i] * ATT_SCALE;
    __syncthreads();
    if (tid < 49) {
        const float* kp = qkwin + (size_t)(n * 49 + tid) * 512 + 256;
        float d = 0.f;
        for (int cc = 0; cc < 256; ++cc) d += qv[cc] * kp[cc];
        lg[tid] = d;
    }
    __syncthreads();
    if (tid == 0) {
        #pragma unroll
        for (int t = 0; t < 4; ++t) {
            float best = -1e30f; int bi = 0;
            for (int j = 0; j < 49; ++j)
                if (lg[j] > best) { best = lg[j]; bi = j; }
            lg[bi] = -1e30f;
            ridx[w * 4 + t] = bi;
        }
    }
}

// ---------------- MFMA attention v2: S^T/O^T operand order, Ps overlays Ks ----------------
// block = (window, head), 4 waves x 16 queries.
// LDS: Vt[32][264] | X region = Ks[256][40] (during S) then Ps[4][16][264] (after)
__global__ __launch_bounds__(256) void attn_mfma_k(const short* __restrict__ qkv,
                                                   const int* __restrict__ ridx,
                                                   short* __restrict__ attn) {
    const int blk = blockIdx.x;
    const int w = blk >> 3, h = blk & 7;
    const int n = w / 49;
    const int tid = threadIdx.x;
    const int wave = tid >> 6, lane = tid & 63;
    const int l15 = lane & 15, quad = lane >> 4;

    __shared__ __align__(16) short smem[25344];   // 50.7KB total
    short* Vt = smem;           // [32][264]
    short* Ks = smem + 8448;    // [256][40] — dead after S
    short* Ps = smem + 8448;    // [4][16][264] — overlays Ks
    __shared__ int rs4[4];
    if (tid < 4) rs4[tid] = ridx[w * 4 + tid];
    __syncthreads();

    // stage K: [key][dim] pad 40
    {
        int s = tid >> 2, kq = (tid & 3) * 8;
        #pragma unroll
        for (int u = 0; u < 4; ++u) {
            int key = u * 64 + s;
            const short* src = qkv + ((size_t)(n * 49 + rs4[u]) * 64 + s) * 768 + 256 + h * 32 + kq;
            *(short8*)&Ks[key * 40 + kq] = *(const short8*)src;
        }
    }
    // stage V transposed, pair-packed b32 writes: thread = (key-pair, dim-half)
    {
        int kp = tid & 127, dh = tid >> 7;
        int k0 = kp * 2;
        int t = k0 >> 6, s = k0 & 63;
        const short* src0 = qkv + ((size_t)(n * 49 + rs4[t]) * 64 + s) * 768 + 512 + h * 32 + dh * 16;
        const short* src1 = src0 + 768;   // key k0+1, same routed window (k0 even)
        short8 a0 = *(const short8*)src0, a1 = *(const short8*)(src0 + 8);
        short8 b0 = *(const short8*)src1, b1 = *(const short8*)(src1 + 8);
        #pragma unroll
        for (int d = 0; d < 8; ++d) {
            *(unsigned*)&Vt[(dh * 16 + d) * 264 + k0] =
                (unsigned)(unsigned short)a0[d] | ((unsigned)(unsigned short)b0[d] << 16);
            *(unsigned*)&Vt[(dh * 16 + 8 + d) * 264 + k0] =
                (unsigned)(unsigned short)a1[d] | ((unsigned)(unsigned short)b1[d] << 16);
        }
    }
    __syncthreads();

    // Q fragment direct from global (B operand: n=q=l15, k=dim)
    const short* qp = qkv + ((size_t)w * 64 + wave * 16 + l15) * 768 + h * 32 + quad * 8;
    short8 qf = *(const short8*)qp;

    // S^T = K·Q^T : st[j][r] = S[key=j*16+quad*4+r][q=l15]
    f32x4 st[16];
    #pragma unroll
    for (int j = 0; j < 16; ++j) {
        short8 kf = *(const short8*)&Ks[(j * 16 + l15) * 40 + quad * 8];
        st[j] = __builtin_amdgcn_mfma_f32_16x16x32_bf16(kf, qf, (f32x4){0.f, 0.f, 0.f, 0.f}, 0, 0, 0);
    }

    // per-q max: in-lane over 64 keys, then across quads
    float mx = -1e30f;
    #pragma unroll
    for (int j = 0; j < 16; ++j)
        #pragma unroll
        for (int r = 0; r < 4; ++r) mx = fmaxf(mx, st[j][r]);
    mx = fmaxf(mx, __shfl_xor(mx, 16));
    mx = fmaxf(mx, __shfl_xor(mx, 32));

    __syncthreads();   // ALL waves done reading Ks before Ps overwrites it

    // exp + packed b64 P writes (P[q][key] layout, stride 264)
    short* pw = &Ps[wave * 16 * 264];
    float sum = 0.f;
    #pragma unroll
    for (int j = 0; j < 16; ++j) {
        short4v pv;
        #pragma unroll
        for (int r = 0; r < 4; ++r) {
            float p = __expf((st[j][r] - mx) * ATT_SCALE);
            sum += p;
            pv[r] = f2bs(p);
        }
        *(short4v*)&pw[l15 * 264 + j * 16 + quad * 4] = pv;
    }
    sum += __shfl_xor(sum, 16);
    sum += __shfl_xor(sum, 32);
    float inv = 1.f / sum;
    __builtin_amdgcn_s_waitcnt(0);   // wave-local: P writes visible to own reads

    // O^T = V^T·P^T : A=Vt (m=dim), B=P (n=q)
    f32x4 oc[2] = {(f32x4){0.f,0.f,0.f,0.f}, (f32x4){0.f,0.f,0.f,0.f}};
    #pragma unroll
    for (int kk = 0; kk < 8; ++kk) {
        short8 pf = *(const short8*)&pw[l15 * 264 + kk * 32 + quad * 8];
        #pragma unroll
        for (int jj = 0; jj < 2; ++jj) {
            short8 vf = *(const short8*)&Vt[(jj * 16 + l15) * 264 + kk * 32 + quad * 8];
            oc[jj] = __builtin_amdgcn_mfma_f32_16x16x32_bf16(vf, pf, oc[jj], 0, 0, 0);
        }
    }

    // oc[jj][r] = O[q=l15][d=jj*16+quad*4+r] -> packed b64 stores
    short* op = attn + ((size_t)w * 64 + wave * 16 + l15) * 256 + h * 32;
    #pragma unroll
    for (int jj = 0; jj < 2; ++jj) {
        short4v o4;
        #pragma unroll
        for (int r = 0; r < 4; ++r) o4[r] = f2bs(oc[jj][r] * inv);
        *(short4v*)&op[jj * 16 + quad * 4] = o4;
    }
}

// ---------------- LePE 5x5 dwconv + combine (vectorized 8-ch per thread) ----------------
__global__ __launch_bounds__(256) void lepe_k(const short* __restrict__ qkv,
                                              const short* __restrict__ attn,
                                              const float* __restrict__ lw,
                                              const float* __restrict__ lb,
                                              short* __restrict__ ywo) {
    int t = blockIdx.x * 8 + (threadIdx.x >> 5);
    int c0 = (threadIdx.x & 31) * 8;
    int n = t / 3136, rem = t % 3136, y = rem / 56, x = rem % 56;
    float sum[8];
    {
        float4 b0 = *(const float4*)(lb + c0), b1 = *(const float4*)(lb + c0 + 4);
        sum[0] = b0.x; sum[1] = b0.y; sum[2] = b0.z; sum[3] = b0.w;
        sum[4] = b1.x; sum[5] = b1.y; sum[6] = b1.z; sum[7] = b1.w;
    }
    #pragma unroll
    for (int ky = 0; ky < 5; ++ky) {
        int yy = y + ky - 2;
        if ((unsigned)yy >= 56u) continue;
        #pragma unroll
        for (int kx = 0; kx < 5; ++kx) {
            int xx = x + kx - 2;
            if ((unsigned)xx >= 56u) continue;
            int p = (yy >> 3) * 7 + (xx >> 3);
            int si = (yy & 7) * 8 + (xx & 7);
            short8 v = *(const short8*)(qkv + ((size_t)(n * 49 + p) * 64 + si) * 768 + 512 + c0);
            const float* wp = lw + (ky * 5 + kx) * 256 + c0;
            float4 w0 = *(const float4*)wp, w1 = *(const float4*)(wp + 4);
            sum[0] += bs2f(v[0]) * w0.x; sum[1] += bs2f(v[1]) * w0.y;
            sum[2] += bs2f(v[2]) * w0.z; sum[3] += bs2f(v[3]) * w0.w;
            sum[4] += bs2f(v[4]) * w1.x; sum[5] += bs2f(v[5]) * w1.y;
            sum[6] += bs2f(v[6]) * w1.z; sum[7] += bs2f(v[7]) * w1.w;
        }
    }
    int p0 = (y >> 3) * 7 + (x >> 3);
    int s0 = (y & 7) * 8 + (x & 7);
    short8 a = *(const short8*)(attn + ((size_t)(n * 49 + p0) * 64 + s0) * 256 + c0);
    short8 o;
    #pragma unroll
    for (int i = 0; i < 8; ++i) o[i] = f2bs(sum[i] + bs2f(a[i]));
    *(short8*)(ywo + (size_t)t * 256 + c0) = o;
}

extern "C" void kernel_launch(void* const* d_in, const int* in_sizes, int n_in,
                              void* d_out, int out_size, void* d_ws, size_t ws_size,
                              hipStream_t stream) {
    const float* x      = (const float*)d_in[0];
    const float* ln1_g  = (const float*)d_in[1];
    const float* ln1_b  = (const float*)d_in[2];
    const float* qkv_w  = (const float*)d_in[3];
    const float* qkv_b  = (const float*)d_in[4];
    const float* lepe_w = (const float*)d_in[5];
    const float* lepe_b = (const float*)d_in[6];
    const float* wo_w   = (const float*)d_in[7];
    const float* wo_b   = (const float*)d_in[8];
    const float* ln2_g  = (const float*)d_in[9];
    const float* ln2_b  = (const float*)d_in[10];
    const float* mlp_w1 = (const float*)d_in[11];
    const float* mlp_b1 = (const float*)d_in[12];
    const float* mlp_w2 = (const float*)d_in[13];
    const float* mlp_b2 = (const float*)d_in[14];
    float* out = (float*)d_out;

    char* ws = (char*)d_ws;
    __hip_bfloat16* wqkvT = (__hip_bfloat16*)(ws + OFF_WQKV);
    __hip_bfloat16* wwoT  = (__hip_bfloat16*)(ws + OFF_WWO);
    __hip_bfloat16* w1T   = (__hip_bfloat16*)(ws + OFF_W1);
    __hip_bfloat16* w2T   = (__hip_bfloat16*)(ws + OFF_W2);
    short* xln   = (short*)(ws + OFF_XLN);
    short* qkvb  = (short*)(ws + OFF_QKV);
    float* qkwin = (float*)(ws + OFF_QKWIN);
    int*   ridx  = (int*)(ws + OFF_RIDX);
    short* attnb = (short*)(ws + OFF_ATTN);
    short* ywo   = (short*)(ws + OFF_XLN);    // reuse
    short* h2    = (short*)(ws + OFF_ATTN);   // reuse
    short* hmid  = (short*)(ws + OFF_HMID);   // reuse XLN+QKV span

    // 0. all weights -> bf16 transposed (N x K), one launch
    transpose_cast4_k<<<768, 256, 0, stream>>>(qkv_w, wo_w, mlp_w1, mlp_w2,
                                               wqkvT, wwoT, w1T, w2T);
    // 1. LN1 -> xln bf16 (window order)
    ln_bf_k<<<TOK/4, 256, 0, stream>>>(x, ln1_g, ln1_b, xln, 1);
    // 2. qkv GEMM -> bf16
    gemm64<0><<<dim3(6, 392), 256, 0, stream>>>(xln, (const short*)wqkvT,
                                                qkv_b, nullptr, qkvb, TOK, 768, 256);
    // 3. window means
    win_means_k<<<NPW, 256, 0, stream>>>(qkvb, qkwin);
    // 4. routing
    route_k<<<NPW, 64, 0, stream>>>(qkwin, ridx);
    // 5. attention (MFMA) -> bf16
    attn_mfma_k<<<NPW * 8, 256, 0, stream>>>(qkvb, ridx, attnb);
    // 6. lepe + combine -> ywo bf16 (image order)
    lepe_k<<<TOK/8, 256, 0, stream>>>(qkvb, attnb, lepe_w, lepe_b, ywo);
    // 7. wo GEMM + x residual -> d_out f32
    gemm64<1><<<dim3(2, 392), 256, 0, stream>>>(ywo, (const short*)wwoT,
                                                wo_b, x, out, TOK, 256, 256);
    // 8. LN2 -> h2 bf16
    ln_bf_k<<<TOK/4, 256, 0, stream>>>(out, ln2_g, ln2_b, h2, 0);
    // 9. MLP1 GEMM + gelu -> hmid bf16
    gemm64<2><<<dim3(8, 392), 256, 0, stream>>>(h2, (const short*)w1T,
                                                mlp_b1, nullptr, hmid, TOK, 1024, 256);
    // 10. MLP2 GEMM + bias + residual -> d_out f32
    gemm64<1><<<dim3(2, 392), 256, 0, stream>>>(hmid, (const short*)w2T,
                                                mlp_b2, out, out, TOK, 256, 1024);
}